// Round 9
// baseline (442.560 us; speedup 1.0000x reference)
//
#include <hip/hip_runtime.h>
#include <cstdint>

// ---------------------------------------------------------------------------
// q[256][262144], s[512][262144] fp32.
// rank by d2 ~ s2[n] - 2*(q.s)[m][n]; per-row top-10 -> threshold -> row mask
// out = q * mask[row]
// K1: split-K GEMM, BM=BN=128 BK=32, 8 waves x (64x32 wave tile), 2 blocks/CU
//     -> 4 waves/SIMD TLP. fp32 DMA'd to LDS via global_load_lds (XOR-swizzled
//     source + swizzled read, linear dest); fp32->bf16 hi/lo split in consume;
//     3-term MFMA (qh*sh+qh*sl+ql*sh); counted-vmcnt 2-phase schedule.
// K2: reduce partials + per-row top-10; K3: threshold+mask; K4: masked copy
// ---------------------------------------------------------------------------

typedef __attribute__((ext_vector_type(8))) __bf16 bf16x8;
typedef __attribute__((ext_vector_type(4))) float f32x4;
typedef __attribute__((ext_vector_type(4))) unsigned int uintx4;

#define KTOT 262144
#define MQ 256
#define NS 512
#define KSPLIT 64
#define KC (KTOT / KSPLIT)      // 4096
#define BK 32
#define NSTEPS (KC / BK)        // 128
#define BUFBYTES 32768          // A 16K + B 16K per buffer
#define BOFF 16384              // B offset inside buffer

__device__ inline void gld16(const float* g, void* l) {
    __builtin_amdgcn_global_load_lds(
        (const __attribute__((address_space(1))) void*)g,
        (__attribute__((address_space(3))) void*)l,
        16, 0, 0);
}

__device__ inline unsigned int cvtpk_bf16(float a, float b) {
    unsigned int r;
    asm("v_cvt_pk_bf16_f32 %0, %1, %2" : "=v"(r) : "v"(a), "v"(b));
    return r; // r[15:0]=bf16(a), r[31:16]=bf16(b)
}

__device__ inline void split2(float a, float b, unsigned int& h, unsigned int& l) {
    h = cvtpk_bf16(a, b);
    float ra = a - __uint_as_float(h << 16);          // exact (Sterbenz)
    float rb = b - __uint_as_float(h & 0xFFFF0000u);  // exact
    l = cvtpk_bf16(ra, rb);
}

// 8 consecutive fp32 (two float4) -> bf16x8 hi + bf16x8 lo
__device__ inline void split8v(const float4& x, const float4& y, bf16x8& hv, bf16x8& lv) {
    unsigned int h0, h1, h2, h3, l0, l1, l2, l3;
    split2(x.x, x.y, h0, l0);
    split2(x.z, x.w, h1, l1);
    split2(y.x, y.y, h2, l2);
    split2(y.z, y.w, h3, l3);
    uintx4 h = (uintx4){h0, h1, h2, h3};
    uintx4 l = (uintx4){l0, l1, l2, l3};
    hv = __builtin_bit_cast(bf16x8, h);
    lv = __builtin_bit_cast(bf16x8, l);
}

// ---------------------------------------------------------------------------
// K1: grid = 512 = 64 chunks x 2 mtiles x 4 ntiles, XCD-swizzled so a chunk's
// 8 sibling blocks co-run on one XCD (L2 reuse of the k-slice).
// block = 512 threads (8 waves, 2x4 wave grid, wave tile 64x32).
// ---------------------------------------------------------------------------
__global__ __launch_bounds__(512, 4)
void k1_gemm(const float* __restrict__ Q, const float* __restrict__ S,
             float* __restrict__ Ppart, float* __restrict__ s2part)
{
    __shared__ __align__(16) unsigned char Lds[2 * BUFBYTES];   // 64 KiB

    const int tid  = threadIdx.x;
    const int lane = tid & 63;
    const int w    = tid >> 6;            // wave 0..7
    const int wm   = w >> 2;              // 0..1 : 64-row band
    const int wn   = w & 3;               // 0..3 : 32-col band
    const int lr   = lane & 15;
    const int lk   = lane >> 4;

    const int phys = blockIdx.x;
    const int xcd  = phys & 7;
    const int ord  = phys >> 3;           // 0..63
    const int chunk = xcd * 8 + (ord >> 3);
    const int sub  = ord & 7;
    const int mtile = sub >> 2;           // 0..1
    const int ntile = sub & 3;            // 0..3
    const long k0  = (long)chunk * KC;

    // --- staging source pointers: 4 global_load_lds per thread per step.
    // slot s = i*512 + tid covers LDS 16B-slot s (linear dest);
    // source chunk is XOR-swizzled: LDS slot (row,u) <- global chunk u^(row&7).
    const float* gsrc[4];
#pragma unroll
    for (int i = 0; i < 4; ++i) {
        int s    = i * 512 + tid;              // 0..2047
        int tile = s >> 10;                    // 0 = A, 1 = B
        int r    = (s & 1023) >> 3;            // row 0..127
        int u    = s & 7;                      // 16B slot within row
        int c    = u ^ (r & 7);                // swizzled source chunk
        const float* base = tile ? (S + (long)(ntile * 128 + r) * KTOT)
                                 : (Q + (long)(mtile * 128 + r) * KTOT);
        gsrc[i] = base + k0 + c * 4;
    }

    // --- LDS read byte-offsets (swizzled to match): row r, float4 chunk c
    // lives at byte r*128 + (c^(r&7))*16 (+BOFF for B).
    int aoffB[4][2], boffB[2][2];
#pragma unroll
    for (int i = 0; i < 4; ++i) {
        int ra = wm * 64 + i * 16 + lr;        // ra&7 == lr&7
#pragma unroll
        for (int t = 0; t < 2; ++t)
            aoffB[i][t] = ra * 128 + ((lk * 2 + t) ^ (lr & 7)) * 16;
    }
#pragma unroll
    for (int j = 0; j < 2; ++j) {
        int rb = wn * 32 + j * 16 + lr;        // rb&7 == lr&7
#pragma unroll
        for (int t = 0; t < 2; ++t)
            boffB[j][t] = BOFF + rb * 128 + ((lk * 2 + t) ^ (lr & 7)) * 16;
    }

    f32x4 acc[4][2];
#pragma unroll
    for (int i = 0; i < 4; ++i)
#pragma unroll
        for (int j = 0; j < 2; ++j)
            acc[i][j] = (f32x4){0.f, 0.f, 0.f, 0.f};
    float ssq[2] = {0.f, 0.f};

#define STAGE(BUFBASE)                                                    \
    {                                                                     \
        _Pragma("unroll")                                                 \
        for (int i = 0; i < 4; ++i) {                                     \
            gld16(gsrc[i], &Lds[(BUFBASE) + i * 8192 + w * 1024]);        \
            gsrc[i] += BK;                                                \
        }                                                                 \
    }

    STAGE(0)                               // tile 0 -> buf0
    for (int s = 0; s < NSTEPS; ++s) {
        const int cur = (s & 1) * BUFBYTES;
        // counted vmcnt: issue next tile's DMA first; its 4 loads stay in
        // flight across both barriers; only tile s's 4 loads are awaited.
        if (s + 1 < NSTEPS) {
            STAGE(((s + 1) & 1) * BUFBYTES)
            asm volatile("s_waitcnt vmcnt(4)" ::: "memory");
        } else {
            asm volatile("s_waitcnt vmcnt(0)" ::: "memory");
        }
        __builtin_amdgcn_sched_barrier(0);
        __builtin_amdgcn_s_barrier();      // all waves: buf[cur] fully written
        __builtin_amdgcn_sched_barrier(0);

        // consume: B frags (held), then stream A frags; 24 MFMAs
        bf16x8 bh[2], bl[2];
#pragma unroll
        for (int j = 0; j < 2; ++j) {
            float4 u = *(const float4*)&Lds[cur + boffB[j][0]];
            float4 v = *(const float4*)&Lds[cur + boffB[j][1]];
            split8v(u, v, bh[j], bl[j]);
            ssq[j] += u.x*u.x + u.y*u.y + u.z*u.z + u.w*u.w
                    + v.x*v.x + v.y*v.y + v.z*v.z + v.w*v.w;
        }
#pragma unroll
        for (int i = 0; i < 4; ++i) {
            float4 x = *(const float4*)&Lds[cur + aoffB[i][0]];
            float4 y = *(const float4*)&Lds[cur + aoffB[i][1]];
            bf16x8 ah, al;
            split8v(x, y, ah, al);
#pragma unroll
            for (int j = 0; j < 2; ++j) {
                acc[i][j] = __builtin_amdgcn_mfma_f32_16x16x32_bf16(ah, bh[j], acc[i][j], 0, 0, 0);
                acc[i][j] = __builtin_amdgcn_mfma_f32_16x16x32_bf16(ah, bl[j], acc[i][j], 0, 0, 0);
                acc[i][j] = __builtin_amdgcn_mfma_f32_16x16x32_bf16(al, bh[j], acc[i][j], 0, 0, 0);
            }
        }

        // end-of-step barrier: next STAGE may not overwrite buf[cur] until
        // every wave's reads completed (lgkm drained before its MFMAs).
        __builtin_amdgcn_sched_barrier(0);
        __builtin_amdgcn_s_barrier();
        __builtin_amdgcn_sched_barrier(0);
    }
#undef STAGE

    // s2 partials: lane ssq[j] covers B row wn*32+j*16+lr, k-quarter lk.
    // wm and mtile duplicate the computation -> gate writes.
#pragma unroll
    for (int j = 0; j < 2; ++j) {
        float v = ssq[j];
        v += __shfl_xor(v, 16);
        v += __shfl_xor(v, 32);
        if (lk == 0 && wm == 0 && mtile == 0)
            s2part[chunk * NS + ntile * 128 + wn * 32 + j * 16 + lr] = v;
    }

    // write q.s partial tile  (C/D layout: col=lane&15, row=(lane>>4)*4+reg)
    float* op = Ppart + (long)chunk * (MQ * NS);
#pragma unroll
    for (int i = 0; i < 4; ++i)
#pragma unroll
        for (int j = 0; j < 2; ++j) {
            int mb = mtile * 128 + wm * 64 + i * 16 + lk * 4;
            int nn = ntile * 128 + wn * 32 + j * 16 + lr;
#pragma unroll
            for (int r = 0; r < 4; ++r)
                op[(long)(mb + r) * NS + nn] = acc[i][j][r];
        }
}

// ---------------------------------------------------------------------------
// K2: one block per query row: reduce K-split partials -> d2 row -> top-10
// ---------------------------------------------------------------------------
__global__ __launch_bounds__(256)
void k2_topk(const float* __restrict__ Ppart, const float* __restrict__ s2part,
             int* __restrict__ idxb)
{
    __shared__ float d2s[NS];
    const int m = blockIdx.x;
    const int tid = threadIdx.x;
    for (int nn = tid; nn < NS; nn += 256) {
        float s2 = 0.f, p = 0.f;
        for (int c = 0; c < KSPLIT; ++c) {
            s2 += s2part[c * NS + nn];
            p  += Ppart[(long)c * (MQ * NS) + (long)m * NS + nn];
        }
        d2s[nn] = s2 - 2.f * p;
    }
    __syncthreads();
    if (tid < 64) {
        unsigned long long key[8];
#pragma unroll
        for (int j = 0; j < 8; ++j) {
            int n = tid * 8 + j;
            unsigned int u = __float_as_uint(d2s[n]);
            u = (u >> 31) ? ~u : (u | 0x80000000u);   // total order, ascending
            key[j] = ((unsigned long long)u << 32) | (unsigned int)n;
        }
        for (int it = 0; it < 10; ++it) {
            unsigned long long best = key[0];
#pragma unroll
            for (int j = 1; j < 8; ++j) best = key[j] < best ? key[j] : best;
            for (int d = 1; d < 64; d <<= 1) {
                unsigned long long o = __shfl_xor(best, d);
                best = o < best ? o : best;
            }
            if (tid == 0) idxb[m * 10 + it] = (int)(best & 0xFFFFFFFFu);
#pragma unroll
            for (int j = 0; j < 8; ++j) if (key[j] == best) key[j] = ~0ull;
        }
    }
}

// ---------------------------------------------------------------------------
// K3: losses / best_k / threshold / mask  (integer sums < 2^24 -> exact fp32)
// ---------------------------------------------------------------------------
__global__ __launch_bounds__(256)
void k3_thresh(const int* __restrict__ idxb, float* __restrict__ mask)
{
    __shared__ int colsum[10];
    __shared__ float thr;
    const int tid = threadIdx.x;
    if (tid < 10) {
        int s = 0;
        for (int m = 0; m < MQ; ++m) s += idxb[m * 10 + tid];
        colsum[tid] = s;
    }
    __syncthreads();
    if (tid == 0) {
        float pre = 0.f, best = 3.4e38f;
        for (int k = 1; k <= 10; ++k) {
            pre += (float)colsum[k - 1];
            float loss = pre / (256.0f * (float)k);
            if (loss < best) best = loss;   // first-min == argmin; threshold = losses[best_k]
        }
        thr = best;
    }
    __syncthreads();
    if (tid < MQ) mask[tid] = ((float)idxb[tid * 10] < thr) ? 1.0f : 0.0f;
}

// ---------------------------------------------------------------------------
// K4: out = q * mask[row]   (float4, 2^18 floats per row)
// ---------------------------------------------------------------------------
__global__ __launch_bounds__(256)
void k4_apply(const float* __restrict__ Q, const float* __restrict__ mask,
              float* __restrict__ out)
{
    long i = ((long)blockIdx.x * 256 + threadIdx.x) * 4;
    int row = (int)(i >> 18);
    float4 v = *(const float4*)(Q + i);
    float mm = mask[row];
    v.x *= mm; v.y *= mm; v.z *= mm; v.w *= mm;
    *(float4*)(out + i) = v;
}

extern "C" void kernel_launch(void* const* d_in, const int* in_sizes, int n_in,
                              void* d_out, int out_size, void* d_ws, size_t ws_size,
                              hipStream_t stream)
{
    const float* Q = (const float*)d_in[0];
    const float* S = (const float*)d_in[1];
    float* out = (float*)d_out;

    // scratch inside d_out (overwritten by k4 afterwards); only mask must
    // survive into k4, so it lives in d_ws.
    float* Ppart  = out;                                   // 64*256*512 f32 = 32 MiB
    float* s2part = out + (long)KSPLIT * MQ * NS;          // 64*512 f32
    int*   idxb   = (int*)(s2part + KSPLIT * NS);          // 256*10 int
    float* mask   = (float*)d_ws;                          // 256 f32

    hipLaunchKernelGGL(k1_gemm,  dim3(512),   dim3(512), 0, stream, Q, S, Ppart, s2part);
    hipLaunchKernelGGL(k2_topk,  dim3(MQ),    dim3(256), 0, stream, Ppart, s2part, idxb);
    hipLaunchKernelGGL(k3_thresh,dim3(1),     dim3(256), 0, stream, idxb, mask);
    hipLaunchKernelGGL(k4_apply, dim3(65536), dim3(256), 0, stream, Q, mask, out);
}

// Round 10
// 394.621 us; speedup vs baseline: 1.1215x; 1.1215x over previous
//
#include <hip/hip_runtime.h>
#include <cstdint>

// ---------------------------------------------------------------------------
// q[256][262144], s[512][262144] fp32.
// rank by d2 ~ s2[n] - 2*(q.s)[m][n]; per-row top-10 -> threshold -> row mask
// out = q * mask[row]
// K1: m201-style 8-phase (here 4-phase/K-step) 256x256-tile split-K GEMM.
//     Reg-staged fp32 -> bf16 hi/lo split ONCE at staging; LDS rows
//     [256][128B] = hi(4 slots)+lo(4 slots), XOR-swizzled (slot ^ row&7).
//     Per phase: ds_read quadrant -> barrier -> lgkm(0) -> setprio(1) ->
//     24 MFMA -> setprio(0); P0 issues next tile's global loads (T14 early),
//     P3 splits+writes them (T14 late) under the MFMA shadow.
// K2: reduce partials + per-row top-10; K3: threshold+mask; K4: masked copy
// ---------------------------------------------------------------------------

typedef __attribute__((ext_vector_type(8))) __bf16 bf16x8;
typedef __attribute__((ext_vector_type(4))) float f32x4;
typedef __attribute__((ext_vector_type(4))) unsigned int uintx4;

#define KTOT 262144
#define MQ 256
#define NS 512
#define KSPLIT 128
#define KC 2048                 // KTOT / KSPLIT
#define BK 32
#define NSTEPS 64               // KC / BK
#define BBASE 32768             // B region offset inside a buffer
#define BUFB 65536              // one buffer: A 32K + B 32K (bf16 hi+lo)

__device__ inline unsigned int cvtpk_bf16(float a, float b) {
    unsigned int r;
    asm("v_cvt_pk_bf16_f32 %0, %1, %2" : "=v"(r) : "v"(a), "v"(b));
    return r; // r[15:0]=bf16(a), r[31:16]=bf16(b)
}

__device__ inline void split2(float a, float b, unsigned int& h, unsigned int& l) {
    h = cvtpk_bf16(a, b);
    float ra = a - __uint_as_float(h << 16);          // exact (Sterbenz)
    float rb = b - __uint_as_float(h & 0xFFFF0000u);  // exact
    l = cvtpk_bf16(ra, rb);
}

__device__ inline void split8u(const float4& x, const float4& y, uintx4& h, uintx4& l) {
    unsigned int h0, h1, h2, h3, l0, l1, l2, l3;
    split2(x.x, x.y, h0, l0);
    split2(x.z, x.w, h1, l1);
    split2(y.x, y.y, h2, l2);
    split2(y.z, y.w, h3, l3);
    h = (uintx4){h0, h1, h2, h3};
    l = (uintx4){l0, l1, l2, l3};
}

#define LDF(OFF) (*(const bf16x8*)&Lds[(OFF)])

#define MM(MI, AH, AL, BH, BL, J)                                                        \
    acc[MI][J] = __builtin_amdgcn_mfma_f32_16x16x32_bf16(AH, BH, acc[MI][J], 0, 0, 0);   \
    acc[MI][J] = __builtin_amdgcn_mfma_f32_16x16x32_bf16(AH, BL, acc[MI][J], 0, 0, 0);   \
    acc[MI][J] = __builtin_amdgcn_mfma_f32_16x16x32_bf16(AL, BH, acc[MI][J], 0, 0, 0);

#define MMROW(MI, AH, AL)                                                                \
    MM(MI, AH, AL, bh0, bl0, 0) MM(MI, AH, AL, bh1, bl1, 1)                              \
    MM(MI, AH, AL, bh2, bl2, 2) MM(MI, AH, AL, bh3, bl3, 3)

#define PH_SYNC                                                                          \
    __builtin_amdgcn_s_barrier();                                                        \
    asm volatile("s_waitcnt lgkmcnt(0)" ::: "memory");                                   \
    __builtin_amdgcn_sched_barrier(0);

#define PH_END                                                                           \
    __builtin_amdgcn_sched_barrier(0);                                                   \
    __builtin_amdgcn_s_barrier();

// ---------------------------------------------------------------------------
// K1: grid = 256 = 128 chunks x 2 ntiles, XCD-swizzled (chunk's pair shares
// the Q k-slice via L2). block = 512 threads (8 waves, 2x4, wave 128x64).
// ---------------------------------------------------------------------------
__global__ __launch_bounds__(512, 2)
void k1_gemm(const float* __restrict__ Q, const float* __restrict__ S,
             float* __restrict__ Ppart, float* __restrict__ s2part)
{
    __shared__ __align__(16) unsigned char Lds[2 * BUFB];   // 128 KiB dbuf

    const int tid  = threadIdx.x;
    const int lane = tid & 63;
    const int w    = tid >> 6;            // wave 0..7
    const int wm   = w >> 2;              // 0..1 : 128-row band
    const int wn   = w & 3;               // 0..3 : 64-col band
    const int lr   = lane & 15;
    const int lk   = lane >> 4;

    const int phys  = blockIdx.x;
    const int xcd   = phys & 7;
    const int ord   = phys >> 3;          // 0..31
    const int chunk = xcd * 16 + (ord >> 1);   // 0..127
    const int ntile = ord & 1;
    const long k0   = (long)chunk * KC;

    // --- staging: thread t handles A row t>>1 and B row t>>1, k-half t&1.
    const int rowh = tid >> 1;
    const int h    = tid & 1;
    const int e    = rowh & 7;
    const float* qsrc = Q + (long)rowh * KTOT + k0 + h * 16;
    const float* ssrc = S + (long)(ntile * 256 + rowh) * KTOT + k0 + h * 16;
    // row layout: 8 x 16B slots; logical slots: hi k[8s..8s+8) at s=0..3,
    // lo at 4+s; phys slot = logical ^ (row&7).
    const int aw0 = rowh * 128 + (((2 * h + 0) ^ e) * 16);  // hi, k-local [0,8)
    const int aw1 = rowh * 128 + (((2 * h + 1) ^ e) * 16);  // hi, k-local [8,16)
    const int aw2 = rowh * 128 + (((2 * h + 4) ^ e) * 16);  // lo, k-local [0,8)
    const int aw3 = rowh * 128 + (((2 * h + 5) ^ e) * 16);  // lo, k-local [8,16)

    // --- frag read bases (row&7 == lr&7 since bands are multiples of 16)
    const int e2  = lr & 7;
    const int aHi = (wm * 128 + lr) * 128 + ((lk ^ e2) * 16);
    const int aLo = (wm * 128 + lr) * 128 + ((((lk + 4)) ^ e2) * 16);
    const int bHi = BBASE + (wn * 64 + lr) * 128 + ((lk ^ e2) * 16);
    const int bLo = BBASE + (wn * 64 + lr) * 128 + ((((lk + 4)) ^ e2) * 16);

    f32x4 acc[8][4];
#pragma unroll
    for (int i = 0; i < 8; ++i)
#pragma unroll
        for (int j = 0; j < 4; ++j)
            acc[i][j] = (f32x4){0.f, 0.f, 0.f, 0.f};

    float ssq = 0.f;
    float4 pa0, pa1, pa2, pa3, pb0, pb1, pb2, pb3;

#define LOADREGS {                                                         \
    pa0 = *(const float4*)(qsrc);      pa1 = *(const float4*)(qsrc + 4);   \
    pa2 = *(const float4*)(qsrc + 8);  pa3 = *(const float4*)(qsrc + 12);  \
    pb0 = *(const float4*)(ssrc);      pb1 = *(const float4*)(ssrc + 4);   \
    pb2 = *(const float4*)(ssrc + 8);  pb3 = *(const float4*)(ssrc + 12);  \
    qsrc += BK; ssrc += BK; }

#define SPLITSTORE(BASE) {                                                 \
    uintx4 u0, u1, u2, u3, v0, v1, v2, v3;                                 \
    split8u(pa0, pa1, u0, v0);                                             \
    split8u(pa2, pa3, u1, v1);                                             \
    split8u(pb0, pb1, u2, v2);                                             \
    split8u(pb2, pb3, u3, v3);                                             \
    ssq += pb0.x*pb0.x + pb0.y*pb0.y + pb0.z*pb0.z + pb0.w*pb0.w           \
         + pb1.x*pb1.x + pb1.y*pb1.y + pb1.z*pb1.z + pb1.w*pb1.w           \
         + pb2.x*pb2.x + pb2.y*pb2.y + pb2.z*pb2.z + pb2.w*pb2.w           \
         + pb3.x*pb3.x + pb3.y*pb3.y + pb3.z*pb3.z + pb3.w*pb3.w;          \
    *(uintx4*)&Lds[(BASE) + aw0] = u0;                                     \
    *(uintx4*)&Lds[(BASE) + aw1] = u1;                                     \
    *(uintx4*)&Lds[(BASE) + aw2] = v0;                                     \
    *(uintx4*)&Lds[(BASE) + aw3] = v1;                                     \
    *(uintx4*)&Lds[(BASE) + BBASE + aw0] = u2;                             \
    *(uintx4*)&Lds[(BASE) + BBASE + aw1] = u3;                             \
    *(uintx4*)&Lds[(BASE) + BBASE + aw2] = v2;                             \
    *(uintx4*)&Lds[(BASE) + BBASE + aw3] = v3; }

    // prologue: tile 0 -> buf0
    LOADREGS
    SPLITSTORE(0)
    asm volatile("s_waitcnt lgkmcnt(0)" ::: "memory");
    __builtin_amdgcn_s_barrier();

    for (int s = 0; s < NSTEPS; ++s) {
        const int cur  = (s & 1) * BUFB;
        const int nxt  = cur ^ BUFB;
        const bool more = (s + 1 < NSTEPS);
        bf16x8 bh0, bh1, bh2, bh3, bl0, bl1, bl2, bl3;
        bf16x8 a0h, a0l, a1h, a1l;

        // ---- phase 0: B all + A mi{0,1}; issue next tile's global loads
        a0h = LDF(cur + aHi);          a0l = LDF(cur + aLo);
        a1h = LDF(cur + aHi + 2048);   a1l = LDF(cur + aLo + 2048);
        bh0 = LDF(cur + bHi);          bl0 = LDF(cur + bLo);
        bh1 = LDF(cur + bHi + 2048);   bl1 = LDF(cur + bLo + 2048);
        bh2 = LDF(cur + bHi + 4096);   bl2 = LDF(cur + bLo + 4096);
        bh3 = LDF(cur + bHi + 6144);   bl3 = LDF(cur + bLo + 6144);
        if (more) LOADREGS
        PH_SYNC
        __builtin_amdgcn_s_setprio(1);
        MMROW(0, a0h, a0l)
        MMROW(1, a1h, a1l)
        __builtin_amdgcn_s_setprio(0);
        PH_END

        // ---- phase 1: A mi{2,3}
        a0h = LDF(cur + aHi + 4096);   a0l = LDF(cur + aLo + 4096);
        a1h = LDF(cur + aHi + 6144);   a1l = LDF(cur + aLo + 6144);
        PH_SYNC
        __builtin_amdgcn_s_setprio(1);
        MMROW(2, a0h, a0l)
        MMROW(3, a1h, a1l)
        __builtin_amdgcn_s_setprio(0);
        PH_END

        // ---- phase 2: A mi{4,5}
        a0h = LDF(cur + aHi + 8192);   a0l = LDF(cur + aLo + 8192);
        a1h = LDF(cur + aHi + 10240);  a1l = LDF(cur + aLo + 10240);
        PH_SYNC
        __builtin_amdgcn_s_setprio(1);
        MMROW(4, a0h, a0l)
        MMROW(5, a1h, a1l)
        __builtin_amdgcn_s_setprio(0);
        PH_END

        // ---- phase 3: A mi{6,7}; then split+write next tile under MFMA shadow
        a0h = LDF(cur + aHi + 12288);  a0l = LDF(cur + aLo + 12288);
        a1h = LDF(cur + aHi + 14336);  a1l = LDF(cur + aLo + 14336);
        PH_SYNC
        __builtin_amdgcn_s_setprio(1);
        MMROW(6, a0h, a0l)
        MMROW(7, a1h, a1l)
        __builtin_amdgcn_s_setprio(0);
        if (more) SPLITSTORE(nxt)
        asm volatile("s_waitcnt lgkmcnt(0)" ::: "memory");
        PH_END
    }
#undef LOADREGS
#undef SPLITSTORE

    // s2 partials: thread's ssq covers B row rowh (k-half h) over full KC.
    float o = __shfl_xor(ssq, 1);
    if (h == 0)
        s2part[chunk * NS + ntile * 256 + rowh] = ssq + o;

    // write q.s partial tile  (C/D layout: col=lane&15, row=(lane>>4)*4+reg)
    float* op = Ppart + (long)chunk * (MQ * NS);
#pragma unroll
    for (int mi = 0; mi < 8; ++mi)
#pragma unroll
        for (int nj = 0; nj < 4; ++nj) {
            int mb = wm * 128 + mi * 16 + lk * 4;
            int nn = ntile * 256 + wn * 64 + nj * 16 + lr;
#pragma unroll
            for (int r = 0; r < 4; ++r)
                op[(long)(mb + r) * NS + nn] = acc[mi][nj][r];
        }
}

// ---------------------------------------------------------------------------
// K2: one block per query row: reduce K-split partials -> d2 row -> top-10
// ---------------------------------------------------------------------------
__global__ __launch_bounds__(256)
void k2_topk(const float* __restrict__ Ppart, const float* __restrict__ s2part,
             int* __restrict__ idxb)
{
    __shared__ float d2s[NS];
    const int m = blockIdx.x;
    const int tid = threadIdx.x;
    for (int nn = tid; nn < NS; nn += 256) {
        float s2 = 0.f, p = 0.f;
        for (int c = 0; c < KSPLIT; ++c) {
            s2 += s2part[c * NS + nn];
            p  += Ppart[(long)c * (MQ * NS) + (long)m * NS + nn];
        }
        d2s[nn] = s2 - 2.f * p;
    }
    __syncthreads();
    if (tid < 64) {
        unsigned long long key[8];
#pragma unroll
        for (int j = 0; j < 8; ++j) {
            int n = tid * 8 + j;
            unsigned int u = __float_as_uint(d2s[n]);
            u = (u >> 31) ? ~u : (u | 0x80000000u);   // total order, ascending
            key[j] = ((unsigned long long)u << 32) | (unsigned int)n;
        }
        for (int it = 0; it < 10; ++it) {
            unsigned long long best = key[0];
#pragma unroll
            for (int j = 1; j < 8; ++j) best = key[j] < best ? key[j] : best;
            for (int d = 1; d < 64; d <<= 1) {
                unsigned long long o = __shfl_xor(best, d);
                best = o < best ? o : best;
            }
            if (tid == 0) idxb[m * 10 + it] = (int)(best & 0xFFFFFFFFu);
#pragma unroll
            for (int j = 0; j < 8; ++j) if (key[j] == best) key[j] = ~0ull;
        }
    }
}

// ---------------------------------------------------------------------------
// K3: losses / best_k / threshold / mask  (integer sums < 2^24 -> exact fp32)
// ---------------------------------------------------------------------------
__global__ __launch_bounds__(256)
void k3_thresh(const int* __restrict__ idxb, float* __restrict__ mask)
{
    __shared__ int colsum[10];
    __shared__ float thr;
    const int tid = threadIdx.x;
    if (tid < 10) {
        int s = 0;
        for (int m = 0; m < MQ; ++m) s += idxb[m * 10 + tid];
        colsum[tid] = s;
    }
    __syncthreads();
    if (tid == 0) {
        float pre = 0.f, best = 3.4e38f;
        for (int k = 1; k <= 10; ++k) {
            pre += (float)colsum[k - 1];
            float loss = pre / (256.0f * (float)k);
            if (loss < best) best = loss;   // first-min == argmin; threshold = losses[best_k]
        }
        thr = best;
    }
    __syncthreads();
    if (tid < MQ) mask[tid] = ((float)idxb[tid * 10] < thr) ? 1.0f : 0.0f;
}

// ---------------------------------------------------------------------------
// K4: out = q * mask[row]   (float4, 2^18 floats per row)
// ---------------------------------------------------------------------------
__global__ __launch_bounds__(256)
void k4_apply(const float* __restrict__ Q, const float* __restrict__ mask,
              float* __restrict__ out)
{
    long i = ((long)blockIdx.x * 256 + threadIdx.x) * 4;
    int row = (int)(i >> 18);
    float4 v = *(const float4*)(Q + i);
    float mm = mask[row];
    v.x *= mm; v.y *= mm; v.z *= mm; v.w *= mm;
    *(float4*)(out + i) = v;
}

extern "C" void kernel_launch(void* const* d_in, const int* in_sizes, int n_in,
                              void* d_out, int out_size, void* d_ws, size_t ws_size,
                              hipStream_t stream)
{
    const float* Q = (const float*)d_in[0];
    const float* S = (const float*)d_in[1];
    float* out = (float*)d_out;

    // scratch inside d_out (overwritten by k4 afterwards); only mask must
    // survive into k4, so it lives in d_ws.
    float* Ppart  = out;                                   // 128*256*512 f32 = 64 MiB
    float* s2part = out + (long)KSPLIT * MQ * NS;          // 128*512 f32
    int*   idxb   = (int*)(s2part + KSPLIT * NS);          // 256*10 int
    float* mask   = (float*)d_ws;                          // 256 f32

    hipLaunchKernelGGL(k1_gemm,  dim3(256),   dim3(512), 0, stream, Q, S, Ppart, s2part);
    hipLaunchKernelGGL(k2_topk,  dim3(MQ),    dim3(256), 0, stream, Ppart, s2part, idxb);
    hipLaunchKernelGGL(k3_thresh,dim3(1),     dim3(256), 0, stream, idxb, mask);
    hipLaunchKernelGGL(k4_apply, dim3(65536), dim3(256), 0, stream, Q, mask, out);
}

// Round 11
// 383.240 us; speedup vs baseline: 1.1548x; 1.0297x over previous
//
#include <hip/hip_runtime.h>
#include <cstdint>

// ---------------------------------------------------------------------------
// q[256][262144], s[512][262144] fp32.
// rank by d2 ~ s2[n] - 2*(q.s)[m][n]; per-row top-10 -> threshold -> row mask
// out = q * mask[row]
// K1: 256x256-tile split-K GEMM, ONE barrier per K-step (no intra-step
//     barriers: all subtile reads hit the same buffer -> no hazard; the
//     compiler software-pipelines ds_read vs MFMA with counted lgkmcnt).
//     Reg-staged fp32 -> bf16 hi/lo split once; LDS rows [256][128B]
//     XOR-swizzled; 3-term MFMA (qh*sh + qh*sl + ql*sh).
// K2: reduce partials + per-row top-10; K3: threshold+mask; K4: masked copy
// ---------------------------------------------------------------------------

typedef __attribute__((ext_vector_type(8))) __bf16 bf16x8;
typedef __attribute__((ext_vector_type(4))) float f32x4;
typedef __attribute__((ext_vector_type(4))) unsigned int uintx4;

#define KTOT 262144
#define MQ 256
#define NS 512
#define KSPLIT 128
#define KC 2048                 // KTOT / KSPLIT
#define BK 32
#define NSTEPS 64               // KC / BK
#define BBASE 32768             // B region offset inside a buffer
#define BUFB 65536              // one buffer: A 32K + B 32K (bf16 hi+lo)

__device__ inline unsigned int cvtpk_bf16(float a, float b) {
    unsigned int r;
    asm("v_cvt_pk_bf16_f32 %0, %1, %2" : "=v"(r) : "v"(a), "v"(b));
    return r; // r[15:0]=bf16(a), r[31:16]=bf16(b)
}

__device__ inline void split2(float a, float b, unsigned int& h, unsigned int& l) {
    h = cvtpk_bf16(a, b);
    float ra = a - __uint_as_float(h << 16);          // exact (Sterbenz)
    float rb = b - __uint_as_float(h & 0xFFFF0000u);  // exact
    l = cvtpk_bf16(ra, rb);
}

__device__ inline void split8u(const float4& x, const float4& y, uintx4& h, uintx4& l) {
    unsigned int h0, h1, h2, h3, l0, l1, l2, l3;
    split2(x.x, x.y, h0, l0);
    split2(x.z, x.w, h1, l1);
    split2(y.x, y.y, h2, l2);
    split2(y.z, y.w, h3, l3);
    h = (uintx4){h0, h1, h2, h3};
    l = (uintx4){l0, l1, l2, l3};
}

#define LDF(OFF) (*(const bf16x8*)&Lds[(OFF)])

#define MM(MI, AH, AL, BH, BL, J)                                                        \
    acc[MI][J] = __builtin_amdgcn_mfma_f32_16x16x32_bf16(AH, BH, acc[MI][J], 0, 0, 0);   \
    acc[MI][J] = __builtin_amdgcn_mfma_f32_16x16x32_bf16(AH, BL, acc[MI][J], 0, 0, 0);   \
    acc[MI][J] = __builtin_amdgcn_mfma_f32_16x16x32_bf16(AL, BH, acc[MI][J], 0, 0, 0);

#define MMROW(MI, AH, AL)                                                                \
    MM(MI, AH, AL, bh0, bl0, 0) MM(MI, AH, AL, bh1, bl1, 1)                              \
    MM(MI, AH, AL, bh2, bl2, 2) MM(MI, AH, AL, bh3, bl3, 3)

// ---------------------------------------------------------------------------
// K1: grid = 256 = 128 chunks x 2 ntiles, XCD-swizzled (chunk's pair shares
// the Q k-slice via L2). block = 512 threads (8 waves, 2x4, wave 128x64).
// ---------------------------------------------------------------------------
__global__ __launch_bounds__(512, 2)
void k1_gemm(const float* __restrict__ Q, const float* __restrict__ S,
             float* __restrict__ Ppart, float* __restrict__ s2part)
{
    __shared__ __align__(16) unsigned char Lds[2 * BUFB];   // 128 KiB dbuf

    const int tid  = threadIdx.x;
    const int lane = tid & 63;
    const int w    = tid >> 6;            // wave 0..7
    const int wm   = w >> 2;              // 0..1 : 128-row band
    const int wn   = w & 3;               // 0..3 : 64-col band
    const int lr   = lane & 15;
    const int lk   = lane >> 4;

    const int phys  = blockIdx.x;
    const int xcd   = phys & 7;
    const int ord   = phys >> 3;          // 0..31
    const int chunk = xcd * 16 + (ord >> 1);   // 0..127
    const int ntile = ord & 1;
    const long k0   = (long)chunk * KC;

    // --- staging: thread t handles A row t>>1 and B row t>>1, k-half t&1.
    const int rowh = tid >> 1;
    const int h    = tid & 1;
    const int e    = rowh & 7;
    const float* qsrc = Q + (long)rowh * KTOT + k0 + h * 16;
    const float* ssrc = S + (long)(ntile * 256 + rowh) * KTOT + k0 + h * 16;
    // row layout: 8 x 16B slots; logical: hi k[8s..8s+8) at s=0..3, lo at 4+s;
    // phys slot = logical ^ (row&7).
    const int aw0 = rowh * 128 + (((2 * h + 0) ^ e) * 16);  // hi, k-local [0,8)
    const int aw1 = rowh * 128 + (((2 * h + 1) ^ e) * 16);  // hi, k-local [8,16)
    const int aw2 = rowh * 128 + (((2 * h + 4) ^ e) * 16);  // lo, k-local [0,8)
    const int aw3 = rowh * 128 + (((2 * h + 5) ^ e) * 16);  // lo, k-local [8,16)

    // --- frag read bases (row&7 == lr&7 since bands are multiples of 16)
    const int e2  = lr & 7;
    const int aHi = (wm * 128 + lr) * 128 + ((lk ^ e2) * 16);
    const int aLo = (wm * 128 + lr) * 128 + (((lk + 4) ^ e2) * 16);
    const int bHi = BBASE + (wn * 64 + lr) * 128 + ((lk ^ e2) * 16);
    const int bLo = BBASE + (wn * 64 + lr) * 128 + (((lk + 4) ^ e2) * 16);

    f32x4 acc[8][4];
#pragma unroll
    for (int i = 0; i < 8; ++i)
#pragma unroll
        for (int j = 0; j < 4; ++j)
            acc[i][j] = (f32x4){0.f, 0.f, 0.f, 0.f};

    float ssq = 0.f;
    float4 pa0, pa1, pa2, pa3, pb0, pb1, pb2, pb3;

#define LOADREGS {                                                         \
    pa0 = *(const float4*)(qsrc);      pa1 = *(const float4*)(qsrc + 4);   \
    pa2 = *(const float4*)(qsrc + 8);  pa3 = *(const float4*)(qsrc + 12);  \
    pb0 = *(const float4*)(ssrc);      pb1 = *(const float4*)(ssrc + 4);   \
    pb2 = *(const float4*)(ssrc + 8);  pb3 = *(const float4*)(ssrc + 12);  \
    qsrc += BK; ssrc += BK; }

#define SPLITSTORE(BASE) {                                                 \
    uintx4 u0, u1, u2, u3, v0, v1, v2, v3;                                 \
    split8u(pa0, pa1, u0, v0);                                             \
    split8u(pa2, pa3, u1, v1);                                             \
    split8u(pb0, pb1, u2, v2);                                             \
    split8u(pb2, pb3, u3, v3);                                             \
    ssq += pb0.x*pb0.x + pb0.y*pb0.y + pb0.z*pb0.z + pb0.w*pb0.w           \
         + pb1.x*pb1.x + pb1.y*pb1.y + pb1.z*pb1.z + pb1.w*pb1.w           \
         + pb2.x*pb2.x + pb2.y*pb2.y + pb2.z*pb2.z + pb2.w*pb2.w           \
         + pb3.x*pb3.x + pb3.y*pb3.y + pb3.z*pb3.z + pb3.w*pb3.w;          \
    *(uintx4*)&Lds[(BASE) + aw0] = u0;                                     \
    *(uintx4*)&Lds[(BASE) + aw1] = u1;                                     \
    *(uintx4*)&Lds[(BASE) + aw2] = v0;                                     \
    *(uintx4*)&Lds[(BASE) + aw3] = v1;                                     \
    *(uintx4*)&Lds[(BASE) + BBASE + aw0] = u2;                             \
    *(uintx4*)&Lds[(BASE) + BBASE + aw1] = u3;                             \
    *(uintx4*)&Lds[(BASE) + BBASE + aw2] = v2;                             \
    *(uintx4*)&Lds[(BASE) + BBASE + aw3] = v3; }

    // prologue: tile 0 staged to buf0; tile 1 loads issued
    LOADREGS                                   // tile 0 -> staging regs
    SPLITSTORE(0)                              // staging -> buf0
    LOADREGS                                   // tile 1 -> staging (in flight)
    asm volatile("s_waitcnt lgkmcnt(0)" ::: "memory");
    __builtin_amdgcn_s_barrier();
    __builtin_amdgcn_sched_barrier(0);

    for (int s = 0; s < NSTEPS; ++s) {
        const int cur = (s & 1) * BUFB;
        const int nxt = cur ^ BUFB;

        // stage tile s+1 into the other buffer (no reader this step), then
        // issue tile s+2's global loads: a full step of latency cover.
        if (s + 1 < NSTEPS) SPLITSTORE(nxt)
        if (s + 2 < NSTEPS) LOADREGS

        // consume buffer cur: straight-line reads + 96 MFMAs; the compiler
        // pipelines ds_read -> MFMA with counted lgkmcnt (no barriers here).
        bf16x8 bh0 = LDF(cur + bHi);          bf16x8 bl0 = LDF(cur + bLo);
        bf16x8 bh1 = LDF(cur + bHi + 2048);   bf16x8 bl1 = LDF(cur + bLo + 2048);
        bf16x8 bh2 = LDF(cur + bHi + 4096);   bf16x8 bl2 = LDF(cur + bLo + 4096);
        bf16x8 bh3 = LDF(cur + bHi + 6144);   bf16x8 bl3 = LDF(cur + bLo + 6144);
#pragma unroll
        for (int mi = 0; mi < 8; ++mi) {
            bf16x8 ah = LDF(cur + aHi + mi * 2048);
            bf16x8 al = LDF(cur + aLo + mi * 2048);
            MMROW(mi, ah, al)
        }

        // step boundary: my ds_writes of nxt drained; all waves sync.
        asm volatile("s_waitcnt lgkmcnt(0)" ::: "memory");
        __builtin_amdgcn_s_barrier();
        __builtin_amdgcn_sched_barrier(0);
    }
#undef LOADREGS
#undef SPLITSTORE

    // s2 partials: thread's ssq covers B row rowh (k-half h) over full KC.
    float o = __shfl_xor(ssq, 1);
    if (h == 0)
        s2part[chunk * NS + ntile * 256 + rowh] = ssq + o;

    // write q.s partial tile  (C/D layout: col=lane&15, row=(lane>>4)*4+reg)
    float* op = Ppart + (long)chunk * (MQ * NS);
#pragma unroll
    for (int mi = 0; mi < 8; ++mi)
#pragma unroll
        for (int nj = 0; nj < 4; ++nj) {
            int mb = wm * 128 + mi * 16 + lk * 4;
            int nn = ntile * 256 + wn * 64 + nj * 16 + lr;
#pragma unroll
            for (int r = 0; r < 4; ++r)
                op[(long)(mb + r) * NS + nn] = acc[mi][nj][r];
        }
}

// ---------------------------------------------------------------------------
// K2: one block per query row: reduce K-split partials -> d2 row -> top-10
// ---------------------------------------------------------------------------
__global__ __launch_bounds__(256)
void k2_topk(const float* __restrict__ Ppart, const float* __restrict__ s2part,
             int* __restrict__ idxb)
{
    __shared__ float d2s[NS];
    const int m = blockIdx.x;
    const int tid = threadIdx.x;
    for (int nn = tid; nn < NS; nn += 256) {
        float s2 = 0.f, p = 0.f;
        for (int c = 0; c < KSPLIT; ++c) {
            s2 += s2part[c * NS + nn];
            p  += Ppart[(long)c * (MQ * NS) + (long)m * NS + nn];
        }
        d2s[nn] = s2 - 2.f * p;
    }
    __syncthreads();
    if (tid < 64) {
        unsigned long long key[8];
#pragma unroll
        for (int j = 0; j < 8; ++j) {
            int n = tid * 8 + j;
            unsigned int u = __float_as_uint(d2s[n]);
            u = (u >> 31) ? ~u : (u | 0x80000000u);   // total order, ascending
            key[j] = ((unsigned long long)u << 32) | (unsigned int)n;
        }
        for (int it = 0; it < 10; ++it) {
            unsigned long long best = key[0];
#pragma unroll
            for (int j = 1; j < 8; ++j) best = key[j] < best ? key[j] : best;
            for (int d = 1; d < 64; d <<= 1) {
                unsigned long long o = __shfl_xor(best, d);
                best = o < best ? o : best;
            }
            if (tid == 0) idxb[m * 10 + it] = (int)(best & 0xFFFFFFFFu);
#pragma unroll
            for (int j = 0; j < 8; ++j) if (key[j] == best) key[j] = ~0ull;
        }
    }
}

// ---------------------------------------------------------------------------
// K3: losses / best_k / threshold / mask  (integer sums < 2^24 -> exact fp32)
// ---------------------------------------------------------------------------
__global__ __launch_bounds__(256)
void k3_thresh(const int* __restrict__ idxb, float* __restrict__ mask)
{
    __shared__ int colsum[10];
    __shared__ float thr;
    const int tid = threadIdx.x;
    if (tid < 10) {
        int s = 0;
        for (int m = 0; m < MQ; ++m) s += idxb[m * 10 + tid];
        colsum[tid] = s;
    }
    __syncthreads();
    if (tid == 0) {
        float pre = 0.f, best = 3.4e38f;
        for (int k = 1; k <= 10; ++k) {
            pre += (float)colsum[k - 1];
            float loss = pre / (256.0f * (float)k);
            if (loss < best) best = loss;   // first-min == argmin; threshold = losses[best_k]
        }
        thr = best;
    }
    __syncthreads();
    if (tid < MQ) mask[tid] = ((float)idxb[tid * 10] < thr) ? 1.0f : 0.0f;
}

// ---------------------------------------------------------------------------
// K4: out = q * mask[row]   (float4, 2^18 floats per row)
// ---------------------------------------------------------------------------
__global__ __launch_bounds__(256)
void k4_apply(const float* __restrict__ Q, const float* __restrict__ mask,
              float* __restrict__ out)
{
    long i = ((long)blockIdx.x * 256 + threadIdx.x) * 4;
    int row = (int)(i >> 18);
    float4 v = *(const float4*)(Q + i);
    float mm = mask[row];
    v.x *= mm; v.y *= mm; v.z *= mm; v.w *= mm;
    *(float4*)(out + i) = v;
}

extern "C" void kernel_launch(void* const* d_in, const int* in_sizes, int n_in,
                              void* d_out, int out_size, void* d_ws, size_t ws_size,
                              hipStream_t stream)
{
    const float* Q = (const float*)d_in[0];
    const float* S = (const float*)d_in[1];
    float* out = (float*)d_out;

    // scratch inside d_out (overwritten by k4 afterwards); only mask must
    // survive into k4, so it lives in d_ws.
    float* Ppart  = out;                                   // 128*256*512 f32 = 64 MiB
    float* s2part = out + (long)KSPLIT * MQ * NS;          // 128*512 f32
    int*   idxb   = (int*)(s2part + KSPLIT * NS);          // 256*10 int
    float* mask   = (float*)d_ws;                          // 256 f32

    hipLaunchKernelGGL(k1_gemm,  dim3(256),   dim3(512), 0, stream, Q, S, Ppart, s2part);
    hipLaunchKernelGGL(k2_topk,  dim3(MQ),    dim3(256), 0, stream, Ppart, s2part, idxb);
    hipLaunchKernelGGL(k3_thresh,dim3(1),     dim3(256), 0, stream, idxb, mask);
    hipLaunchKernelGGL(k4_apply, dim3(65536), dim3(256), 0, stream, Q, mask, out);
}

// Round 12
// 358.315 us; speedup vs baseline: 1.2351x; 1.0696x over previous
//
#include <hip/hip_runtime.h>
#include <cstdint>

// ---------------------------------------------------------------------------
// q[256][262144], s[512][262144] fp32.
// rank by d2 ~ s2[n] - 2*(q.s)[m][n]; per-row top-10 -> threshold -> row mask
// out = q * mask[row]
// K1: 256x128-tile split-K GEMM with ONE barrier/step and an explicit
//     one-batch-lookahead LDS read pipeline (counted lgkmcnt(2), sched_barrier
//     pinned): reads for MFMA batch p+1 are in flight UNDER batch p's MFMAs.
//     MFMAs term-major (4 independent acc chains). Reg-staged fp32->bf16
//     hi/lo split once; LDS [384][128B] XOR-swizzled; 3-term MFMA.
// K2: reduce partials + per-row top-10; K3: threshold+mask; K4: masked copy
// ---------------------------------------------------------------------------

typedef __attribute__((ext_vector_type(8))) __bf16 bf16x8;
typedef __attribute__((ext_vector_type(4))) float f32x4;
typedef __attribute__((ext_vector_type(4))) unsigned int uintx4;

#define KTOT 262144
#define MQ 256
#define NS 512
#define KSPLIT 64
#define KC 4096                 // KTOT / KSPLIT
#define BK 32
#define NSTEPS 128              // KC / BK
#define BBASE 32768             // B region offset (A: 256 rows x 128B)
#define BUFB 49152              // buffer: A 32K + B 16K

__device__ inline unsigned int cvtpk_bf16(float a, float b) {
    unsigned int r;
    asm("v_cvt_pk_bf16_f32 %0, %1, %2" : "=v"(r) : "v"(a), "v"(b));
    return r; // r[15:0]=bf16(a), r[31:16]=bf16(b)
}

__device__ inline void split2(float a, float b, unsigned int& h, unsigned int& l) {
    h = cvtpk_bf16(a, b);
    float ra = a - __uint_as_float(h << 16);          // exact (Sterbenz)
    float rb = b - __uint_as_float(h & 0xFFFF0000u);  // exact
    l = cvtpk_bf16(ra, rb);
}

__device__ inline void split8u(const float4& x, const float4& y, uintx4& h, uintx4& l) {
    unsigned int h0, h1, h2, h3, l0, l1, l2, l3;
    split2(x.x, x.y, h0, l0);
    split2(x.z, x.w, h1, l1);
    split2(y.x, y.y, h2, l2);
    split2(y.z, y.w, h3, l3);
    h = (uintx4){h0, h1, h2, h3};
    l = (uintx4){l0, l1, l2, l3};
}

#define LDF(OFF) (*(const bf16x8*)&Lds[(OFF)])
#define SB __builtin_amdgcn_sched_barrier(0);

// term-major: 4 independent accumulator chains, dependent pairs 4 apart
#define MMB(MI, AH, AL)                                                                     \
    acc[MI][0] = __builtin_amdgcn_mfma_f32_16x16x32_bf16(AH, bh0, acc[MI][0], 0, 0, 0);     \
    acc[MI][1] = __builtin_amdgcn_mfma_f32_16x16x32_bf16(AH, bh1, acc[MI][1], 0, 0, 0);     \
    acc[MI][2] = __builtin_amdgcn_mfma_f32_16x16x32_bf16(AH, bh2, acc[MI][2], 0, 0, 0);     \
    acc[MI][3] = __builtin_amdgcn_mfma_f32_16x16x32_bf16(AH, bh3, acc[MI][3], 0, 0, 0);     \
    acc[MI][0] = __builtin_amdgcn_mfma_f32_16x16x32_bf16(AH, bl0, acc[MI][0], 0, 0, 0);     \
    acc[MI][1] = __builtin_amdgcn_mfma_f32_16x16x32_bf16(AH, bl1, acc[MI][1], 0, 0, 0);     \
    acc[MI][2] = __builtin_amdgcn_mfma_f32_16x16x32_bf16(AH, bl2, acc[MI][2], 0, 0, 0);     \
    acc[MI][3] = __builtin_amdgcn_mfma_f32_16x16x32_bf16(AH, bl3, acc[MI][3], 0, 0, 0);     \
    acc[MI][0] = __builtin_amdgcn_mfma_f32_16x16x32_bf16(AL, bh0, acc[MI][0], 0, 0, 0);     \
    acc[MI][1] = __builtin_amdgcn_mfma_f32_16x16x32_bf16(AL, bh1, acc[MI][1], 0, 0, 0);     \
    acc[MI][2] = __builtin_amdgcn_mfma_f32_16x16x32_bf16(AL, bh2, acc[MI][2], 0, 0, 0);     \
    acc[MI][3] = __builtin_amdgcn_mfma_f32_16x16x32_bf16(AL, bh3, acc[MI][3], 0, 0, 0);

// ---------------------------------------------------------------------------
// K1: grid = 256 = 64 chunks x 4 ntiles, XCD-swizzled (chunk's 4 siblings on
// one XCD -> Q k-slice L2-resident). block = 512 thr (8 waves, 4x2, 64x64).
// ---------------------------------------------------------------------------
__global__ __launch_bounds__(512, 2)
void k1_gemm(const float* __restrict__ Q, const float* __restrict__ S,
             float* __restrict__ Ppart, float* __restrict__ s2part)
{
    __shared__ __align__(16) unsigned char Lds[2 * BUFB];   // 96 KiB dbuf

    const int tid  = threadIdx.x;
    const int lane = tid & 63;
    const int w    = tid >> 6;            // wave 0..7
    const int wm   = w >> 1;              // 0..3 : 64-row band
    const int wn   = w & 1;               // 0..1 : 64-col band
    const int lr   = lane & 15;
    const int lk   = lane >> 4;

    const int phys  = blockIdx.x;
    const int xcd   = phys & 7;
    const int ord   = phys >> 3;          // 0..31
    const int chunk = xcd * 8 + (ord >> 2);    // 0..63
    const int ntile = ord & 3;
    const long k0   = (long)chunk * KC;

    // --- staging: A: thread t -> row t>>1, k-half t&1 (16 floats);
    //              B: thread t -> row t>>2, k-quarter t&3 (8 floats).
    const int ra = tid >> 1, hA = tid & 1;
    const int rb = tid >> 2, qt = tid & 3;
    const float* qsrc = Q + (long)ra * KTOT + k0 + hA * 16;
    const float* ssrc = S + (long)(ntile * 128 + rb) * KTOT + k0 + qt * 8;
    const int eA = ra & 7, eB = rb & 7;
    // A row: 8x16B slots, hi slots 0-3 (k-local 8s..8s+8), lo 4-7; phys=log^ (row&7)
    const int aw0 = ra * 128 + (((2 * hA + 0) ^ eA) * 16);
    const int aw1 = ra * 128 + (((2 * hA + 1) ^ eA) * 16);
    const int aw2 = ra * 128 + (((2 * hA + 4) ^ eA) * 16);
    const int aw3 = ra * 128 + (((2 * hA + 5) ^ eA) * 16);
    const int bw0 = BBASE + rb * 128 + ((qt ^ eB) * 16);
    const int bw1 = BBASE + rb * 128 + (((4 + qt) ^ eB) * 16);

    // --- frag read offsets (row&7 == lr&7: bands are multiples of 16)
    const int e2 = lr & 7;
    int aHi[4], aLo[4], bHiA[4], bLoA[4];
#pragma unroll
    for (int i = 0; i < 4; ++i) {
        int rA = wm * 64 + i * 16 + lr;
        aHi[i] = rA * 128 + ((lk ^ e2) * 16);
        aLo[i] = rA * 128 + (((lk + 4) ^ e2) * 16);
        int rB = wn * 64 + i * 16 + lr;
        bHiA[i] = BBASE + rB * 128 + ((lk ^ e2) * 16);
        bLoA[i] = BBASE + rB * 128 + (((lk + 4) ^ e2) * 16);
    }

    f32x4 acc[4][4];
#pragma unroll
    for (int i = 0; i < 4; ++i)
#pragma unroll
        for (int j = 0; j < 4; ++j)
            acc[i][j] = (f32x4){0.f, 0.f, 0.f, 0.f};

    float ssq = 0.f;
    float4 pa0, pa1, pa2, pa3, pb0, pb1;

#define LOADREGS {                                                         \
    pa0 = *(const float4*)(qsrc);      pa1 = *(const float4*)(qsrc + 4);   \
    pa2 = *(const float4*)(qsrc + 8);  pa3 = *(const float4*)(qsrc + 12);  \
    pb0 = *(const float4*)(ssrc);      pb1 = *(const float4*)(ssrc + 4);   \
    qsrc += BK; ssrc += BK; }

#define SPLITSTORE(BASE) {                                                 \
    uintx4 u0, u1, v0, v1, hb, lb;                                         \
    split8u(pa0, pa1, u0, v0);                                             \
    split8u(pa2, pa3, u1, v1);                                             \
    split8u(pb0, pb1, hb, lb);                                             \
    ssq += pb0.x*pb0.x + pb0.y*pb0.y + pb0.z*pb0.z + pb0.w*pb0.w           \
         + pb1.x*pb1.x + pb1.y*pb1.y + pb1.z*pb1.z + pb1.w*pb1.w;          \
    *(uintx4*)&Lds[(BASE) + aw0] = u0;                                     \
    *(uintx4*)&Lds[(BASE) + aw1] = u1;                                     \
    *(uintx4*)&Lds[(BASE) + aw2] = v0;                                     \
    *(uintx4*)&Lds[(BASE) + aw3] = v1;                                     \
    *(uintx4*)&Lds[(BASE) + bw0] = hb;                                     \
    *(uintx4*)&Lds[(BASE) + bw1] = lb; }

    // prologue: tile0 staged to buf0; tile1 in staging regs
    LOADREGS
    SPLITSTORE(0)
    LOADREGS
    asm volatile("s_waitcnt lgkmcnt(0)" ::: "memory");
    __builtin_amdgcn_s_barrier();
    SB

    for (int s = 0; s < NSTEPS; ++s) {
        const int cur = (s & 1) * BUFB;
        const int nxt = cur ^ BUFB;

        // R0: B all (8 reads) + A0 (2 reads); then writes + global loads.
        bf16x8 bh0 = LDF(cur + bHiA[0]);  bf16x8 bl0 = LDF(cur + bLoA[0]);
        bf16x8 bh1 = LDF(cur + bHiA[1]);  bf16x8 bl1 = LDF(cur + bLoA[1]);
        bf16x8 bh2 = LDF(cur + bHiA[2]);  bf16x8 bl2 = LDF(cur + bLoA[2]);
        bf16x8 bh3 = LDF(cur + bHiA[3]);  bf16x8 bl3 = LDF(cur + bLoA[3]);
        bf16x8 aCh = LDF(cur + aHi[0]);   bf16x8 aCl = LDF(cur + aLo[0]);
        if (s + 1 < NSTEPS) SPLITSTORE(nxt)
        if (s + 2 < NSTEPS) LOADREGS
        SB
        // R1 in flight under MFMA(mi0)
        bf16x8 aNh = LDF(cur + aHi[1]);   bf16x8 aNl = LDF(cur + aLo[1]);
        SB
        asm volatile("s_waitcnt lgkmcnt(2)" ::: "memory");  // R0+W done
        SB
        MMB(0, aCh, aCl)
        SB
        aCh = LDF(cur + aHi[2]);          aCl = LDF(cur + aLo[2]);
        SB
        asm volatile("s_waitcnt lgkmcnt(2)" ::: "memory");  // R1 done
        SB
        MMB(1, aNh, aNl)
        SB
        aNh = LDF(cur + aHi[3]);          aNl = LDF(cur + aLo[3]);
        SB
        asm volatile("s_waitcnt lgkmcnt(2)" ::: "memory");  // R2 done
        SB
        MMB(2, aCh, aCl)
        SB
        asm volatile("s_waitcnt lgkmcnt(0)" ::: "memory");  // R3 + all writes
        SB
        MMB(3, aNh, aNl)
        SB
        __builtin_amdgcn_s_barrier();     // writes of nxt visible to all
        SB
    }
#undef LOADREGS
#undef SPLITSTORE

    // s2 partials: thread covers B row rb, k-quarter qt; reduce 4 lanes.
    {
        float v = ssq + __shfl_xor(ssq, 1);
        v += __shfl_xor(v, 2);
        if (qt == 0)
            s2part[chunk * NS + ntile * 128 + rb] = v;
    }

    // write q.s partial tile  (C/D layout: col=lane&15, row=(lane>>4)*4+reg)
    float* op = Ppart + (long)chunk * (MQ * NS);
#pragma unroll
    for (int mi = 0; mi < 4; ++mi)
#pragma unroll
        for (int nj = 0; nj < 4; ++nj) {
            int mb = wm * 64 + mi * 16 + lk * 4;
            int nn = ntile * 128 + wn * 64 + nj * 16 + lr;
#pragma unroll
            for (int r = 0; r < 4; ++r)
                op[(long)(mb + r) * NS + nn] = acc[mi][nj][r];
        }
}

// ---------------------------------------------------------------------------
// K2: one block per query row: reduce K-split partials -> d2 row -> top-10
// ---------------------------------------------------------------------------
__global__ __launch_bounds__(256)
void k2_topk(const float* __restrict__ Ppart, const float* __restrict__ s2part,
             int* __restrict__ idxb)
{
    __shared__ float d2s[NS];
    const int m = blockIdx.x;
    const int tid = threadIdx.x;
    for (int nn = tid; nn < NS; nn += 256) {
        float s2 = 0.f, p = 0.f;
        for (int c = 0; c < KSPLIT; ++c) {
            s2 += s2part[c * NS + nn];
            p  += Ppart[(long)c * (MQ * NS) + (long)m * NS + nn];
        }
        d2s[nn] = s2 - 2.f * p;
    }
    __syncthreads();
    if (tid < 64) {
        unsigned long long key[8];
#pragma unroll
        for (int j = 0; j < 8; ++j) {
            int n = tid * 8 + j;
            unsigned int u = __float_as_uint(d2s[n]);
            u = (u >> 31) ? ~u : (u | 0x80000000u);   // total order, ascending
            key[j] = ((unsigned long long)u << 32) | (unsigned int)n;
        }
        for (int it = 0; it < 10; ++it) {
            unsigned long long best = key[0];
#pragma unroll
            for (int j = 1; j < 8; ++j) best = key[j] < best ? key[j] : best;
            for (int d = 1; d < 64; d <<= 1) {
                unsigned long long o = __shfl_xor(best, d);
                best = o < best ? o : best;
            }
            if (tid == 0) idxb[m * 10 + it] = (int)(best & 0xFFFFFFFFu);
#pragma unroll
            for (int j = 0; j < 8; ++j) if (key[j] == best) key[j] = ~0ull;
        }
    }
}

// ---------------------------------------------------------------------------
// K3: losses / best_k / threshold / mask  (integer sums < 2^24 -> exact fp32)
// ---------------------------------------------------------------------------
__global__ __launch_bounds__(256)
void k3_thresh(const int* __restrict__ idxb, float* __restrict__ mask)
{
    __shared__ int colsum[10];
    __shared__ float thr;
    const int tid = threadIdx.x;
    if (tid < 10) {
        int s = 0;
        for (int m = 0; m < MQ; ++m) s += idxb[m * 10 + tid];
        colsum[tid] = s;
    }
    __syncthreads();
    if (tid == 0) {
        float pre = 0.f, best = 3.4e38f;
        for (int k = 1; k <= 10; ++k) {
            pre += (float)colsum[k - 1];
            float loss = pre / (256.0f * (float)k);
            if (loss < best) best = loss;   // first-min == argmin; threshold = losses[best_k]
        }
        thr = best;
    }
    __syncthreads();
    if (tid < MQ) mask[tid] = ((float)idxb[tid * 10] < thr) ? 1.0f : 0.0f;
}

// ---------------------------------------------------------------------------
// K4: out = q * mask[row]   (float4, 2^18 floats per row)
// ---------------------------------------------------------------------------
__global__ __launch_bounds__(256)
void k4_apply(const float* __restrict__ Q, const float* __restrict__ mask,
              float* __restrict__ out)
{
    long i = ((long)blockIdx.x * 256 + threadIdx.x) * 4;
    int row = (int)(i >> 18);
    float4 v = *(const float4*)(Q + i);
    float mm = mask[row];
    v.x *= mm; v.y *= mm; v.z *= mm; v.w *= mm;
    *(float4*)(out + i) = v;
}

extern "C" void kernel_launch(void* const* d_in, const int* in_sizes, int n_in,
                              void* d_out, int out_size, void* d_ws, size_t ws_size,
                              hipStream_t stream)
{
    const float* Q = (const float*)d_in[0];
    const float* S = (const float*)d_in[1];
    float* out = (float*)d_out;

    // scratch inside d_out (overwritten by k4 afterwards); only mask must
    // survive into k4, so it lives in d_ws.
    float* Ppart  = out;                                   // 64*256*512 f32 = 32 MiB
    float* s2part = out + (long)KSPLIT * MQ * NS;          // 64*512 f32
    int*   idxb   = (int*)(s2part + KSPLIT * NS);          // 256*10 int
    float* mask   = (float*)d_ws;                          // 256 f32

    hipLaunchKernelGGL(k1_gemm,  dim3(256),   dim3(512), 0, stream, Q, S, Ppart, s2part);
    hipLaunchKernelGGL(k2_topk,  dim3(MQ),    dim3(256), 0, stream, Ppart, s2part, idxb);
    hipLaunchKernelGGL(k3_thresh,dim3(1),     dim3(256), 0, stream, idxb, mask);
    hipLaunchKernelGGL(k4_apply, dim3(65536), dim3(256), 0, stream, Q, mask, out);
}